// Round 5
// baseline (118.049 us; speedup 1.0000x reference)
//
#include <hip/hip_runtime.h>
#include <stdint.h>

typedef unsigned short u16;
typedef __attribute__((ext_vector_type(8))) short shortx8;
typedef __attribute__((ext_vector_type(4))) float floatx4;

#define N_ROWS 8192
#define N_COLS 512
#define KDIM   1024

__device__ __forceinline__ u16 f2bf(float f) {
    union { float f; uint32_t u; } x; x.f = f;
    uint32_t u = x.u;
    uint32_t r = (u + 0x7FFFu + ((u >> 16) & 1u)) >> 16;  // RNE
    return (u16)r;
}

__device__ __forceinline__ void async_copy16(const void* g, void* l) {
    __builtin_amdgcn_global_load_lds(
        (const __attribute__((address_space(1))) void*)g,
        (__attribute__((address_space(3))) void*)l, 16, 0, 0);
}

// ---- kernel 1: fused input prep (+ d_out zero-init) ------------------------
// blocks [0,512): h fp32->bf16 + row |h|^2 (wave-per-row, 4 rows/wave)
// blocks [512,640): protos->bf16 B[c][k]=(pr||pi) + |p|^2 (wave-per-class)
__global__ __launch_bounds__(256) void conv_hp(const float* __restrict__ h,
                                               const float* __restrict__ protos,
                                               u16* __restrict__ hb,
                                               u16* __restrict__ bb,
                                               float* __restrict__ hsq,
                                               float* __restrict__ psq,
                                               float* __restrict__ out) {
    int t = threadIdx.x, lane = t & 63, w = t >> 6;
    int bid = blockIdx.x;
    if (bid == 639 && t < 2) out[t] = 0.0f;     // replaces hipMemsetAsync
    if (bid < 512) {
        int wave = bid * 4 + w;                    // 0..2047
        for (int q = 0; q < 4; q++) {
            int row = wave * 4 + q;
            const float4* src = (const float4*)(h + (size_t)row * KDIM);
            ushort4* dst = (ushort4*)(hb + (size_t)row * KDIM);
            float s = 0.0f;
            #pragma unroll
            for (int j = 0; j < 4; j++) {
                float4 v = src[lane + j * 64];
                s += v.x * v.x + v.y * v.y + v.z * v.z + v.w * v.w;
                dst[lane + j * 64] = make_ushort4(f2bf(v.x), f2bf(v.y), f2bf(v.z), f2bf(v.w));
            }
            #pragma unroll
            for (int off = 32; off; off >>= 1) s += __shfl_xor(s, off);
            if (lane == 0) hsq[row] = s;
        }
    } else {
        int c = (bid - 512) * 4 + w;               // 0..511
        const float4* pr = (const float4*)(protos + (size_t)c * 512);
        const float4* pi = (const float4*)(protos + 512 * 512 + (size_t)c * 512);
        ushort4* dr = (ushort4*)(bb + (size_t)c * KDIM);
        ushort4* di = (ushort4*)(bb + (size_t)c * KDIM + 512);
        float s = 0.0f;
        #pragma unroll
        for (int j = 0; j < 2; j++) {
            float4 a = pr[lane + j * 64];
            float4 b = pi[lane + j * 64];
            s += a.x * a.x + a.y * a.y + a.z * a.z + a.w * a.w;
            s += b.x * b.x + b.y * b.y + b.z * b.z + b.w * b.w;
            dr[lane + j * 64] = make_ushort4(f2bf(a.x), f2bf(a.y), f2bf(a.z), f2bf(a.w));
            di[lane + j * 64] = make_ushort4(f2bf(b.x), f2bf(b.y), f2bf(b.z), f2bf(b.w));
        }
        #pragma unroll
        for (int off = 32; off; off >>= 1) s += __shfl_xor(s, off);
        if (lane == 0) psq[c] = s;
    }
}

// ---- kernel 2: bf16 MFMA GEMM + fused logits + row-partial reduction -------
// BM=128, BN=128, BK=64, 256 threads, 4 waves each 64x64 (acc 4x4) so LDS
// fragment reads per MFMA halve vs 64x32 waves (16 b128 per 32 MFMA).
// Grid 64x4 = 256 blocks = 1 block/CU; double-buffered LDS with the prefetch
// issued AFTER the barrier so the barrier's vmcnt drain only waits on loads
// that had a full compute phase to land.
__global__ __launch_bounds__(256) void gemm_partials(const u16* __restrict__ hb,
                                                     const u16* __restrict__ bb,
                                                     const float* __restrict__ hsq,
                                                     const float* __restrict__ psq,
                                                     const float* __restrict__ radii,
                                                     const int* __restrict__ y,
                                                     const int* __restrict__ slab,
                                                     const int* __restrict__ ninit_p,
                                                     float* __restrict__ pmax_g,
                                                     int* __restrict__ pidx_g,
                                                     float* __restrict__ prmax_g,
                                                     float* __restrict__ pc0_g,
                                                     float* __restrict__ psum_g,
                                                     float* __restrict__ l0arr) {
    constexpr int BM = 128, BN = 128, BK = 64;
    __shared__ __align__(16) u16 As[2][BM * BK];   // 2 x 16 KiB
    __shared__ __align__(16) u16 Bs[2][BN * BK];   // 2 x 16 KiB
    __shared__ float smax[2][128];
    __shared__ int   scol[2][128];
    __shared__ float srmx[2][128];
    __shared__ float sc0v[2][128];
    __shared__ float ssum[2][128];

    int t = threadIdx.x, lane = t & 63, w = t >> 6;
    int wr = (w & 1) * 64;          // wave row offset
    int wc = (w >> 1) * 64;         // wave col offset
    int bm0 = blockIdx.x * BM;
    int bn0 = blockIdx.y * BN;

    // staging: slot s -> row = s>>3, stored kchunk (s&7) holds global kchunk
    // (s&7)^(row&7). Thread t owns slots t+256*i (i<4) in each of As/Bs.
    int tr = t >> 3, tc = t & 7;
    const u16* gA[4]; const u16* gB[4]; int lo[4];
    #pragma unroll
    for (int i = 0; i < 4; i++) {
        int row = tr + 32 * i;
        int kc = tc ^ (row & 7);
        gA[i] = hb + (size_t)(bm0 + row) * KDIM + kc * 8;
        gB[i] = bb + (size_t)(bn0 + row) * KDIM + kc * 8;
        lo[i] = (t + 256 * i) * 8;
    }

    floatx4 acc[4][4] = {};

    int kq = lane >> 4, l7 = lane & 7, m = lane & 15;
    // fragment LDS chunk offsets: global chunk (s*4+kq) at row R stored at
    // chunk (s*4+kq)^(R&7); R&7 == l7 == m&7 for all fragment rows.
    int swz0 = ((kq) ^ l7) * 8;
    int swz1 = ((4 + kq) ^ l7) * 8;

    // preload buffer 0
    #pragma unroll
    for (int i = 0; i < 4; i++) {
        async_copy16(gA[i], &As[0][lo[i]]);
        async_copy16(gB[i], &Bs[0][lo[i]]);
        gA[i] += BK; gB[i] += BK;
    }

    int buf = 0;
    for (int k0 = 0; k0 < KDIM; k0 += BK) {
        __syncthreads();                        // drains current-buf loads
        if (k0 + BK < KDIM) {
            int nb = buf ^ 1;
            #pragma unroll
            for (int i = 0; i < 4; i++) {
                async_copy16(gA[i], &As[nb][lo[i]]);
                async_copy16(gB[i], &Bs[nb][lo[i]]);
                gA[i] += BK; gB[i] += BK;
            }
        }
        const u16* pa = &As[buf][(wr + m) * BK];
        const u16* pb = &Bs[buf][(wc + m) * BK];
        #pragma unroll
        for (int s = 0; s < 2; s++) {
            int sw = s ? swz1 : swz0;
            shortx8 af[4], bf[4];
            #pragma unroll
            for (int i = 0; i < 4; i++) af[i] = *(const shortx8*)(pa + i * 16 * BK + sw);
            #pragma unroll
            for (int j = 0; j < 4; j++) bf[j] = *(const shortx8*)(pb + j * 16 * BK + sw);
            #pragma unroll
            for (int i = 0; i < 4; i++)
                #pragma unroll
                for (int j = 0; j < 4; j++)
                    acc[i][j] = __builtin_amdgcn_mfma_f32_16x16x32_bf16(af[i], bf[j], acc[i][j], 0, 0, 0);
        }
        buf ^= 1;
    }

    // ---- epilogue: logits in-register, reduce 128 cols -> per-row partials -
    // C/D: col = lane&15 (=m), row = kq*4 + reg. Lane's 4 cols:
    int c_[4]; float ps_[4], inv_[4]; int sl_[4];
    #pragma unroll
    for (int j = 0; j < 4; j++) {
        c_[j] = bn0 + wc + j * 16 + m;
        ps_[j] = psq[c_[j]];
        inv_[j] = 0.5f / radii[c_[j]];
        sl_[j] = slab[c_[j]];
    }
    int slabz = slab[0];
    int ninit = ninit_p[0];
    int ch = w >> 1;                 // column half within block
    bool isL0 = (bn0 == 0) && (wc == 0) && (m == 0);

    #pragma unroll
    for (int i = 0; i < 4; i++) {
        #pragma unroll
        for (int r = 0; r < 4; r++) {
            int n = bm0 + wr + i * 16 + kq * 4 + r;
            float hsqn = hsq[n];
            int yv = y[n];
            int lab = (yv >= ninit) ? -1 : yv;
            float v[4];
            #pragma unroll
            for (int j = 0; j < 4; j++)
                v[j] = (2.0f * acc[i][j][r] - hsqn - ps_[j]) * inv_[j];
            if (isL0) l0arr[n] = v[0];               // logits[n][0]

            float bmax = v[0]; int bcol = c_[0];
            float brm = -INFINITY, bc0 = -INFINITY;
            #pragma unroll
            for (int j = 0; j < 4; j++) {
                if (v[j] > bmax) { bmax = v[j]; bcol = c_[j]; } // lower col kept on tie
                if (sl_[j] == lab   && v[j] > brm) brm = v[j];
                if (sl_[j] == slabz && v[j] > bc0) bc0 = v[j];
            }
            #pragma unroll
            for (int off = 1; off < 16; off <<= 1) {   // reduce over 16 lanes
                float ov = __shfl_xor(bmax, off); int oc = __shfl_xor(bcol, off);
                if (ov > bmax || (ov == bmax && oc < bcol)) { bmax = ov; bcol = oc; }
                float orv = __shfl_xor(brm, off); if (orv > brm) brm = orv;
                float oc0 = __shfl_xor(bc0, off); if (oc0 > bc0) bc0 = oc0;
            }
            float se = 0.0f;
            #pragma unroll
            for (int j = 0; j < 4; j++) se += __expf(v[j] - bmax);
            #pragma unroll
            for (int off = 1; off < 16; off <<= 1) se += __shfl_xor(se, off);
            if (m == 0) {
                int rl = (w & 1) * 64 + i * 16 + kq * 4 + r;
                smax[ch][rl] = bmax; scol[ch][rl] = bcol;
                srmx[ch][rl] = brm;  sc0v[ch][rl] = bc0; ssum[ch][rl] = se;
            }
        }
    }
    __syncthreads();
    if (t < 128) {                    // merge the two 64-col halves, write
        int n = bm0 + t;
        size_t gi_ = (size_t)blockIdx.y * N_ROWS + n;
        float m0 = smax[0][t], m1 = smax[1][t];
        int i0 = scol[0][t], i1 = scol[1][t];
        float gm; int gi;
        if (m0 > m1 || (m0 == m1 && i0 < i1)) { gm = m0; gi = i0; }
        else { gm = m1; gi = i1; }
        pmax_g[gi_] = gm;
        pidx_g[gi_] = gi;
        prmax_g[gi_] = fmaxf(srmx[0][t], srmx[1][t]);
        pc0_g[gi_]  = fmaxf(sc0v[0][t], sc0v[1][t]);
        psum_g[gi_] = ssum[0][t] * __expf(m0 - gm) + ssum[1][t] * __expf(m1 - gm);
    }
}

// ---- kernel 3: combine 4 column-block partials per row -> loss, acc --------
__global__ __launch_bounds__(256) void combine(const float* __restrict__ pmax_g,
                                               const int* __restrict__ pidx_g,
                                               const float* __restrict__ prmax_g,
                                               const float* __restrict__ pc0_g,
                                               const float* __restrict__ psum_g,
                                               const float* __restrict__ l0arr,
                                               const int* __restrict__ y,
                                               const int* __restrict__ slab,
                                               const int* __restrict__ ninit_p,
                                               float* __restrict__ out) {
    int t = threadIdx.x, lane = t & 63, w = t >> 6;
    int n = blockIdx.x * 256 + t;

    float gm = -INFINITY; int gi = 0x7fffffff;
    float rm = -INFINITY, c0m = -INFINITY;
    float pm[4];
    #pragma unroll
    for (int cb = 0; cb < 4; cb++) {
        size_t idx = (size_t)cb * N_ROWS + n;
        float p = pmax_g[idx]; int pi = pidx_g[idx];
        pm[cb] = p;
        if (p > gm || (p == gm && pi < gi)) { gm = p; gi = pi; }
        rm = fmaxf(rm, prmax_g[idx]);
        c0m = fmaxf(c0m, pc0_g[idx]);
    }
    float den = 0.0f;
    #pragma unroll
    for (int cb = 0; cb < 4; cb++)
        den += psum_g[(size_t)cb * N_ROWS + n] * __expf(pm[cb] - gm);
    float lse = gm + __logf(den);

    int yv = y[n];
    int lab = (yv >= ninit_p[0]) ? -1 : yv;
    float nll, wgt;
    if (rm != -INFINITY) { nll = lse - rm; wgt = 1.0f; }
    else {                                   // all-(-inf) argmax -> col 0
        float l0 = l0arr[n];
        nll = lse - l0;
        wgt = (l0 == c0m) ? 1.0f : 0.0f;
    }
    int ypred = slab[gi];
    float li = nll * wgt * (1.0f / (float)N_ROWS);
    float ai = (ypred == lab) ? 1.0f : 0.0f;

    #pragma unroll
    for (int off = 32; off; off >>= 1) {
        li += __shfl_xor(li, off);
        ai += __shfl_xor(ai, off);
    }
    __shared__ float pl[4], pa_[4];
    if (lane == 0) { pl[w] = li; pa_[w] = ai; }
    __syncthreads();
    if (t == 0) {
        atomicAdd(&out[0], pl[0] + pl[1] + pl[2] + pl[3]);
        atomicAdd(&out[1], pa_[0] + pa_[1] + pa_[2] + pa_[3]);
    }
}

extern "C" void kernel_launch(void* const* d_in, const int* in_sizes, int n_in,
                              void* d_out, int out_size, void* d_ws, size_t ws_size,
                              hipStream_t stream) {
    const float* h      = (const float*)d_in[0];
    const float* protos = (const float*)d_in[1];
    const float* radii  = (const float*)d_in[2];
    const int*   y      = (const int*)d_in[3];
    const int*   slab   = (const int*)d_in[4];
    const int*   ninit  = (const int*)d_in[5];
    float* out = (float*)d_out;

    char* ws = (char*)d_ws;
    u16*   hb    = (u16*)(ws);                       // 16 MiB
    u16*   bb    = (u16*)(ws + 16777216);            // 1 MiB
    float* hsq   = (float*)(ws + 17825792);          // 32 KiB
    float* psq   = (float*)(ws + 17858560);          // 2 KiB
    float* pmax  = (float*)(ws + 17860608);
    int*   pidx  = (int*)  (ws + 18122752);
    float* prmax = (float*)(ws + 18384896);
    float* pc0   = (float*)(ws + 18647040);
    float* psum  = (float*)(ws + 18909184);
    float* l0arr = (float*)(ws + 19171328);          // 32 KiB

    conv_hp<<<640, 256, 0, stream>>>(h, protos, hb, bb, hsq, psq, out);
    dim3 g(N_ROWS / 128, N_COLS / 128);
    gemm_partials<<<g, 256, 0, stream>>>(hb, bb, hsq, psq, radii, y, slab, ninit,
                                         pmax, pidx, prmax, pc0, psum, l0arr);
    combine<<<N_ROWS / 256, 256, 0, stream>>>(pmax, pidx, prmax, pc0, psum,
                                              l0arr, y, slab, ninit, out);
}